// Round 10
// baseline (340.319 us; speedup 1.0000x reference)
//
#include <hip/hip_runtime.h>

#define T_STEPS 256
#define BATCH   128
#define DIM     1024
#define NROWS   (T_STEPS * BATCH)        // 32768
#define TOTROWS (NROWS + 2 * BATCH)      // 33024

typedef float vfloat4 __attribute__((ext_vector_type(4)));

// ws float-offset layout
#define WS_M     0                        // float[4096]
#define WS_V     4096                     // float[4]
#define WS_CB    4128                     // float[4]
#define WS_QX    8192                     // float4[32768], layout [b][t]
#define WS_HSEQ  (WS_QX + 4 * NROWS)      // float[32768],  layout [b][t]
#define WS_CFIN  (WS_HSEQ + NROWS)       // float[128]

// ---------- prep: M = Wq@Wi via LDS reduce (no atomics, no memset); zero v/cb ----------
__global__ __launch_bounds__(256) void k_prep(const float* __restrict__ Wi,
                                              const float* __restrict__ Wq,
                                              float* __restrict__ M,
                                              float* __restrict__ v,
                                              float* __restrict__ cb) {
    int blk  = blockIdx.x;
    int tid  = threadIdx.x;
    if (blk < 16) {
        int lane = tid & 63;
        int jq   = tid >> 6;                  // j-quarter 0..3
        int d    = blk * 64 + lane;
        float a0 = 0.f, a1 = 0.f, a2 = 0.f, a3 = 0.f;
        int j0 = jq * 256;
        #pragma unroll 4
        for (int j = j0; j < j0 + 256; j++) {
            float wv = Wi[(size_t)j * DIM + d];   // 256B coalesced per wave
            a0 += Wq[0 * DIM + j] * wv;           // uniform -> scalar loads
            a1 += Wq[1 * DIM + j] * wv;
            a2 += Wq[2 * DIM + j] * wv;
            a3 += Wq[3 * DIM + j] * wv;
        }
        __shared__ float sm[4][64][4];
        sm[jq][lane][0] = a0; sm[jq][lane][1] = a1;
        sm[jq][lane][2] = a2; sm[jq][lane][3] = a3;
        __syncthreads();
        if (tid < 64) {
            #pragma unroll
            for (int w = 0; w < 4; w++)
                M[w * DIM + blk * 64 + tid] =
                    sm[0][tid][w] + sm[1][tid][w] + sm[2][tid][w] + sm[3][tid][w];
        }
    } else {                                  // block 16: zero v / cb
        if (tid < 4)      v[tid]      = 0.f;
        else if (tid < 8) cb[tid - 4] = 0.f;
    }
}

// ---------- qx[b][t] = x[row] @ M.T (blocks 0..1023) + v/cb accumulation (blocks 1024..1087) ----------
__global__ __launch_bounds__(256) void k_qx(const float* __restrict__ x,
                                            const float* __restrict__ Wh,
                                            const float* __restrict__ bi,
                                            const float* __restrict__ bh,
                                            const float* __restrict__ Wq,
                                            const float* __restrict__ M,
                                            float4* __restrict__ qxT,
                                            float* __restrict__ v,
                                            float* __restrict__ cb) {
    int blk  = blockIdx.x;
    int tid  = threadIdx.x;
    int wave = tid >> 6;
    int lane = tid & 63;

    if (blk >= 1024) {
        // v/cb contributions: 64 blocks cover the 1024 Wh rows
        int j0 = (blk - 1024) * 16 + wave * 4;
        float sv0 = 0.f, sv1 = 0.f, sv2 = 0.f, sv3 = 0.f;
        float sc0 = 0.f, sc1 = 0.f, sc2 = 0.f, sc3 = 0.f;
        #pragma unroll
        for (int jj = 0; jj < 4; jj++) {
            int j = j0 + jj;
            const float4* row = (const float4*)(Wh + (size_t)j * DIM);
            float s = 0.f;
            #pragma unroll
            for (int k = 0; k < 4; k++) {
                float4 t4 = row[k * 64 + lane];
                s += t4.x + t4.y + t4.z + t4.w;
            }
            #pragma unroll
            for (int off = 32; off; off >>= 1) s += __shfl_xor(s, off, 64);
            float bsum = bi[j] + bh[j];
            float q0 = Wq[0 * DIM + j], q1 = Wq[1 * DIM + j];
            float q2 = Wq[2 * DIM + j], q3 = Wq[3 * DIM + j];
            sv0 += q0 * s;    sv1 += q1 * s;    sv2 += q2 * s;    sv3 += q3 * s;
            sc0 += q0 * bsum; sc1 += q1 * bsum; sc2 += q2 * bsum; sc3 += q3 * bsum;
        }
        if (lane == 0) {
            unsafeAtomicAdd(&v[0], sv0);  unsafeAtomicAdd(&v[1], sv1);
            unsafeAtomicAdd(&v[2], sv2);  unsafeAtomicAdd(&v[3], sv3);
            unsafeAtomicAdd(&cb[0], sc0); unsafeAtomicAdd(&cb[1], sc1);
            unsafeAtomicAdd(&cb[2], sc2); unsafeAtomicAdd(&cb[3], sc3);
        }
        return;
    }

    float4 m[4][4];                                    // M fragment in regs
    #pragma unroll
    for (int w = 0; w < 4; w++)
        #pragma unroll
        for (int k = 0; k < 4; k++)
            m[w][k] = *(const float4*)(M + w * DIM + k * 256 + lane * 4);

    int nwaves = 1024 * 4;
    for (int r = blk * 4 + wave; r < NROWS; r += nwaves) {
        const float4* row = (const float4*)(x + (size_t)r * DIM);
        float a0 = 0.f, a1 = 0.f, a2 = 0.f, a3 = 0.f;
        #pragma unroll
        for (int k = 0; k < 4; k++) {
            float4 xv = row[k * 64 + lane];            // contiguous 1 KB/instr
            a0 += xv.x * m[0][k].x + xv.y * m[0][k].y + xv.z * m[0][k].z + xv.w * m[0][k].w;
            a1 += xv.x * m[1][k].x + xv.y * m[1][k].y + xv.z * m[1][k].z + xv.w * m[1][k].w;
            a2 += xv.x * m[2][k].x + xv.y * m[2][k].y + xv.z * m[2][k].z + xv.w * m[2][k].w;
            a3 += xv.x * m[3][k].x + xv.y * m[3][k].y + xv.z * m[3][k].z + xv.w * m[3][k].w;
        }
        #pragma unroll
        for (int off = 32; off; off >>= 1) {
            a0 += __shfl_xor(a0, off, 64);
            a1 += __shfl_xor(a1, off, 64);
            a2 += __shfl_xor(a2, off, 64);
            a3 += __shfl_xor(a3, off, 64);
        }
        if (lane == 0) {
            int t = r >> 7, b = r & 127;               // transpose: [b][t]
            qxT[(size_t)b * T_STEPS + t] = make_float4(a0, a1, a2, a3);
        }
    }
}

// ---------- recurrence: Padé[5/4] tanh (valid: |c|<=0.762, g in (0,1)), 10 trans/step ----------
__device__ __forceinline__ void rec_step(float4 q,
                                         float b0, float b1, float b2, float b3,
                                         float v0, float v1, float v2, float v3,
                                         float& h, float& c) {
    float z0 = __cosf(q.x + b0 + h * v0);
    float z1 = __cosf(q.y + b1 + h * v1);
    float z2 = __cosf(q.z + b2 + h * v2);
    float z3 = __cosf(q.w + b3 + h * v3);
    float p01 = z0 * z1, p23 = z2 * z3;
    float x0 = __expf(z1 * p23);          // e0 = z1 z2 z3
    float x1 = __expf(p01);               // e1 = z0 z1
    float x2 = __expf(p01 * z2);          // e2 = z0 z1 z2
    float x3 = __expf(p01 * p23);         // e3 = z0 z1 z2 z3
    float S  = (x0 + x1) + (x2 + x3);
    // tanh(x2/S), Pade[5/4] scaled by S^4: tanh(u)=u(945+105u^2+u^4)/(945+420u^2+15u^4)
    float x2q = x2 * x2, Sq = S * S;
    float A = Sq * Sq, B = x2q * Sq, C = x2q * x2q;
    float Ng = fmaf(945.f, A, fmaf(105.f, B, C));
    float Dg = fmaf(945.f, A, fmaf(420.f, B, 15.f * C));
    float SD = S * Dg;
    float r1 = __builtin_amdgcn_rcpf(Sq * Dg);
    // c = f*c + i*tanh(g) = [x0*c*S*Dg + x1*x2*Ng] / (S^2*Dg)
    c = fmaf(x0 * c, SD, (x1 * x2) * Ng) * r1;
    // h = (x3/S)*tanh(c) = x3*c*Nc / (S*Dc)
    float cq = c * c;
    float cq2 = cq * cq;
    float Nc = fmaf(105.f, cq, 945.f + cq2);
    float Dc = fmaf(420.f, cq, fmaf(15.f, cq2, 945.f));
    float r2 = __builtin_amdgcn_rcpf(S * Dc);
    h = ((x3 * c) * Nc) * r2;
}

__global__ __launch_bounds__(128) void k_rec(const float* __restrict__ bq,
                                             const float* __restrict__ theta,
                                             const float* __restrict__ v,
                                             const float* __restrict__ cbp,
                                             const float4* __restrict__ qxT,
                                             float* __restrict__ hT,
                                             float* __restrict__ cfin) {
    int b = threadIdx.x;                      // one chain per lane

    float v0 = v[0], v1 = v[1], v2 = v[2], v3 = v[3];
    float b0 = cbp[0] + bq[0] + theta[0];
    float b1 = cbp[1] + bq[1] + theta[1];
    float b2 = cbp[2] + bq[2] + theta[2];
    float b3 = cbp[3] + bq[3] + theta[3];

    const float4* qrow = qxT + (size_t)b * T_STEPS;   // lane-contiguous 4 KB
    float4*       hrow = (float4*)(hT + (size_t)b * T_STEPS);

    float h = 0.f, c = 0.f;
    float4 q0 = qrow[0], q1 = qrow[1], q2 = qrow[2], q3 = qrow[3];
    float4 q4 = qrow[4], q5 = qrow[5], q6 = qrow[6], q7 = qrow[7];

    for (int t = 0; t < T_STEPS; t += 8) {
        float4 n0, n1, n2, n3, n4, n5, n6, n7;
        if (t + 8 < T_STEPS) {                // prefetch next 8 (contiguous 128 B)
            n0 = qrow[t + 8];  n1 = qrow[t + 9];  n2 = qrow[t + 10]; n3 = qrow[t + 11];
            n4 = qrow[t + 12]; n5 = qrow[t + 13]; n6 = qrow[t + 14]; n7 = qrow[t + 15];
        }
        float h0, h1, h2, h3, h4, h5, h6, h7;
        rec_step(q0, b0, b1, b2, b3, v0, v1, v2, v3, h, c); h0 = h;
        rec_step(q1, b0, b1, b2, b3, v0, v1, v2, v3, h, c); h1 = h;
        rec_step(q2, b0, b1, b2, b3, v0, v1, v2, v3, h, c); h2 = h;
        rec_step(q3, b0, b1, b2, b3, v0, v1, v2, v3, h, c); h3 = h;
        rec_step(q4, b0, b1, b2, b3, v0, v1, v2, v3, h, c); h4 = h;
        rec_step(q5, b0, b1, b2, b3, v0, v1, v2, v3, h, c); h5 = h;
        rec_step(q6, b0, b1, b2, b3, v0, v1, v2, v3, h, c); h6 = h;
        rec_step(q7, b0, b1, b2, b3, v0, v1, v2, v3, h, c); h7 = h;
        hrow[(t >> 2) + 0] = make_float4(h0, h1, h2, h3);   // 2 stores / 8 steps
        hrow[(t >> 2) + 1] = make_float4(h4, h5, h6, h7);
        q0 = n0; q1 = n1; q2 = n2; q3 = n3; q4 = n4; q5 = n5; q6 = n6; q7 = n7;
    }
    cfin[b] = c;
}

// ---------- broadcast write: 4 rows per block, nontemporal ----------
__global__ __launch_bounds__(256) void k_write(const float* __restrict__ hT,
                                               const float* __restrict__ cfin,
                                               float* __restrict__ out) {
    int tid  = threadIdx.x;
    int r    = blockIdx.x * 4 + (tid >> 6);
    int lane = tid & 63;

    float val;
    if      (r < NROWS)          val = hT[(size_t)(r & 127) * T_STEPS + (r >> 7)];
    else if (r < NROWS + BATCH)  val = hT[(size_t)(r - NROWS) * T_STEPS + (T_STEPS - 1)];
    else                         val = cfin[r - NROWS - BATCH];

    vfloat4 vv = {val, val, val, val};
    vfloat4* orow = (vfloat4*)(out + (size_t)r * DIM);
    __builtin_nontemporal_store(vv, &orow[0 * 64 + lane]);
    __builtin_nontemporal_store(vv, &orow[1 * 64 + lane]);
    __builtin_nontemporal_store(vv, &orow[2 * 64 + lane]);
    __builtin_nontemporal_store(vv, &orow[3 * 64 + lane]);
}

extern "C" void kernel_launch(void* const* d_in, const int* in_sizes, int n_in,
                              void* d_out, int out_size, void* d_ws, size_t ws_size,
                              hipStream_t stream) {
    const float* inputs = (const float*)d_in[0];
    const float* Wi     = (const float*)d_in[1];
    const float* bi     = (const float*)d_in[2];
    const float* Wh     = (const float*)d_in[3];
    const float* bh     = (const float*)d_in[4];
    const float* Wq     = (const float*)d_in[5];
    const float* bq     = (const float*)d_in[6];
    const float* theta  = (const float*)d_in[7];
    float* out = (float*)d_out;
    float* ws  = (float*)d_ws;

    float*  M    = ws + WS_M;
    float*  v    = ws + WS_V;
    float*  cb   = ws + WS_CB;
    float4* qxT  = (float4*)(ws + WS_QX);
    float*  hT   = ws + WS_HSEQ;
    float*  cfin = ws + WS_CFIN;

    k_prep <<<17,   256, 0, stream>>>(Wi, Wq, M, v, cb);
    k_qx   <<<1088, 256, 0, stream>>>(inputs, Wh, bi, bh, Wq, M, qxT, v, cb);
    k_rec  <<<1,    128, 0, stream>>>(bq, theta, v, cb, qxT, hT, cfin);
    k_write<<<TOTROWS / 4, 256, 0, stream>>>(hT, cfin, out);
}